// Round 1
// baseline (340.328 us; speedup 1.0000x reference)
//
#include <hip/hip_runtime.h>

// SoftPerspectiveShader: barycentric texture sampling + softmax RGB blend.
// Shapes: N=4, H=512, W=512, K=8, F=200000. One thread per pixel.
// Memory-bound: ~225 MB HBM traffic per launch -> ~36 us floor at 6.3 TB/s.

#define KFRAG 8

__global__ __launch_bounds__(256) void soft_shader_kernel(
    const int*   __restrict__ p2f,         // [NP, 8]
    const float* __restrict__ bary,        // [NP, 8, 3]
    const float* __restrict__ zbuf,        // [NP, 8]
    const float* __restrict__ dists,       // [NP, 8]
    const float* __restrict__ face_colors, // [F, 3, 3]
    float*       __restrict__ out,         // [NP, 4]
    int NP)
{
    constexpr float SIGMA_INV = 1.0f / 1e-4f;
    constexpr float GAMMA_INV = 1.0f / 1e-4f;
    constexpr float EPS   = 1e-10f;
    constexpr float ZNEAR = 1.0f;
    constexpr float ZFAR  = 100.0f;

    int p = blockIdx.x * blockDim.x + threadIdx.x;
    if (p >= NP) return;

    // ---- vectorized coalesced loads ----
    const int4* p2f4 = (const int4*)p2f + (size_t)p * 2;
    int4 f0 = p2f4[0];
    int4 f1 = p2f4[1];
    int fid[KFRAG] = {f0.x, f0.y, f0.z, f0.w, f1.x, f1.y, f1.z, f1.w};

    const float4* zb4 = (const float4*)zbuf + (size_t)p * 2;
    float4 z0 = zb4[0], z1 = zb4[1];
    float zb[KFRAG] = {z0.x, z0.y, z0.z, z0.w, z1.x, z1.y, z1.z, z1.w};

    const float4* dd4 = (const float4*)dists + (size_t)p * 2;
    float4 d0 = dd4[0], d1 = dd4[1];
    float dd[KFRAG] = {d0.x, d0.y, d0.z, d0.w, d1.x, d1.y, d1.z, d1.w};

    float bc[KFRAG * 3];
    const float4* bq = (const float4*)bary + (size_t)p * 6;
#pragma unroll
    for (int i = 0; i < 6; ++i) {
        float4 q = bq[i];
        bc[i * 4 + 0] = q.x;
        bc[i * 4 + 1] = q.y;
        bc[i * 4 + 2] = q.z;
        bc[i * 4 + 3] = q.w;
    }

    // ---- per-fragment: prob, z_inv, texel (gather) ----
    float prob[KFRAG], zinv[KFRAG];
    float texr[KFRAG], texg[KFRAG], texb[KFRAG];
    float zmax = EPS;
#pragma unroll
    for (int k = 0; k < KFRAG; ++k) {
        int   f = fid[k];
        float m = (f >= 0) ? 1.0f : 0.0f;
        // sigmoid(-d/sigma) = 1/(1+exp(d/sigma)); masked -> 0
        prob[k] = m / (1.0f + expf(dd[k] * SIGMA_INV));
        zinv[k] = m * ((ZFAR - zb[k]) / (ZFAR - ZNEAR));
        zmax = fmaxf(zmax, zinv[k]);

        int idx = (f > 0) ? f : 0;
        const float* fc = face_colors + (size_t)idx * 9;
        float b0 = bc[k * 3 + 0], b1 = bc[k * 3 + 1], b2 = bc[k * 3 + 2];
        // texel[c] = sum_v bary[v] * fc[v][c]
        texr[k] = fmaf(b0, fc[0], fmaf(b1, fc[3], b2 * fc[6]));
        texg[k] = fmaf(b0, fc[1], fmaf(b1, fc[4], b2 * fc[7]));
        texb[k] = fmaf(b0, fc[2], fmaf(b1, fc[5], b2 * fc[8]));
    }

    // ---- softmax blend ----
    float delta = fmaxf(expf((EPS - zmax) * GAMMA_INV), EPS);
    float denom = delta;
    float r = 0.0f, g = 0.0f, b = 0.0f;
    float keep = 1.0f; // prod(1 - prob) = 1 - alpha
#pragma unroll
    for (int k = 0; k < KFRAG; ++k) {
        float w = prob[k] * expf((zinv[k] - zmax) * GAMMA_INV);
        denom += w;
        r = fmaf(w, texr[k], r);
        g = fmaf(w, texg[k], g);
        b = fmaf(w, texb[k], b);
        keep *= (1.0f - prob[k]);
    }

    float inv = 1.0f / denom;
    float4 o;
    o.x = (r + delta) * inv; // background = (1,1,1): + delta*1/denom
    o.y = (g + delta) * inv;
    o.z = (b + delta) * inv;
    o.w = keep;
    ((float4*)out)[p] = o;
}

extern "C" void kernel_launch(void* const* d_in, const int* in_sizes, int n_in,
                              void* d_out, int out_size, void* d_ws, size_t ws_size,
                              hipStream_t stream) {
    const int*   p2f         = (const int*)d_in[0];
    const float* bary        = (const float*)d_in[1];
    const float* zbuf        = (const float*)d_in[2];
    const float* dists       = (const float*)d_in[3];
    const float* face_colors = (const float*)d_in[4];
    float* out = (float*)d_out;

    int NP = in_sizes[0] / KFRAG; // N*H*W pixels
    int block = 256;
    int grid = (NP + block - 1) / block;
    soft_shader_kernel<<<grid, block, 0, stream>>>(
        p2f, bary, zbuf, dists, face_colors, out, NP);
}

// Round 2
// 226.995 us; speedup vs baseline: 1.4993x; 1.4993x over previous
//
#include <hip/hip_runtime.h>

// SoftPerspectiveShader: barycentric texture sampling + softmax RGB blend.
// N=4, H=W=512, K=8, F=200000. One thread per pixel.
//
// R1: gate the random face_colors gather on weight magnitude. zbuf is sorted,
// so exp((z_inv - z_max)/1e-4) underflows to 0 (exactly, in f32 — matching
// the reference) unless z_inv is within ~1.2e-3 of z_max. Expected gathered
// fragments: ~1.01 per pixel instead of 8 -> ~8x less gather miss traffic.

#define KFRAG 8

__global__ __launch_bounds__(256) void soft_shader_kernel(
    const int*   __restrict__ p2f,         // [NP, 8]
    const float* __restrict__ bary,        // [NP, 8, 3]
    const float* __restrict__ zbuf,        // [NP, 8]
    const float* __restrict__ dists,       // [NP, 8]
    const float* __restrict__ face_colors, // [F, 3, 3]
    float*       __restrict__ out,         // [NP, 4]
    int NP)
{
    constexpr float SIGMA_INV = 1.0f / 1e-4f;
    constexpr float GAMMA_INV = 1.0f / 1e-4f;
    constexpr float EPS   = 1e-10f;
    constexpr float ZNEAR = 1.0f;
    constexpr float ZFAR  = 100.0f;
    // exp((zinv-zmax)*1e4) < 1e-5  <=>  zinv-zmax < -1.15e-3: contribution
    // < 1e-5 (colors in [0,1], weights normalized) — far under 2e-2 threshold.
    constexpr float ZCUT = -1.2e-3f;

    int p = blockIdx.x * blockDim.x + threadIdx.x;
    if (p >= NP) return;

    // ---- vectorized coalesced loads ----
    const int4* p2f4 = (const int4*)p2f + (size_t)p * 2;
    int4 f0 = p2f4[0];
    int4 f1 = p2f4[1];
    int fid[KFRAG] = {f0.x, f0.y, f0.z, f0.w, f1.x, f1.y, f1.z, f1.w};

    const float4* zb4 = (const float4*)zbuf + (size_t)p * 2;
    float4 z0 = zb4[0], z1 = zb4[1];
    float zb[KFRAG] = {z0.x, z0.y, z0.z, z0.w, z1.x, z1.y, z1.z, z1.w};

    const float4* dd4 = (const float4*)dists + (size_t)p * 2;
    float4 d0 = dd4[0], d1 = dd4[1];
    float dd[KFRAG] = {d0.x, d0.y, d0.z, d0.w, d1.x, d1.y, d1.z, d1.w};

    float bc[KFRAG * 3];
    const float4* bq = (const float4*)bary + (size_t)p * 6;
#pragma unroll
    for (int i = 0; i < 6; ++i) {
        float4 q = bq[i];
        bc[i * 4 + 0] = q.x;
        bc[i * 4 + 1] = q.y;
        bc[i * 4 + 2] = q.z;
        bc[i * 4 + 3] = q.w;
    }

    // ---- per-fragment prob / z_inv; zmax reduction ----
    float prob[KFRAG], zinv[KFRAG];
    float zmax = EPS;
#pragma unroll
    for (int k = 0; k < KFRAG; ++k) {
        float m = (fid[k] >= 0) ? 1.0f : 0.0f;
        // sigmoid(-d/sigma) = 1/(1+exp(d/sigma)); masked -> 0
        prob[k] = m / (1.0f + __expf(dd[k] * SIGMA_INV));
        zinv[k] = m * ((ZFAR - zb[k]) * (1.0f / (ZFAR - ZNEAR)));
        zmax = fmaxf(zmax, zinv[k]);
    }

    // ---- softmax blend with gather gated on weight magnitude ----
    float delta = fmaxf(__expf((EPS - zmax) * GAMMA_INV), EPS);
    float denom = delta;
    float r = 0.0f, g = 0.0f, b = 0.0f;
    float keep = 1.0f; // prod(1 - prob) = 1 - alpha
#pragma unroll
    for (int k = 0; k < KFRAG; ++k) {
        keep *= (1.0f - prob[k]);
        if ((fid[k] >= 0) && (zinv[k] - zmax > ZCUT)) {
            float w = prob[k] * __expf((zinv[k] - zmax) * GAMMA_INV);
            const float* fc = face_colors + (size_t)fid[k] * 9;
            float b0 = bc[k * 3 + 0], b1 = bc[k * 3 + 1], b2 = bc[k * 3 + 2];
            float tr = fmaf(b0, fc[0], fmaf(b1, fc[3], b2 * fc[6]));
            float tg = fmaf(b0, fc[1], fmaf(b1, fc[4], b2 * fc[7]));
            float tb = fmaf(b0, fc[2], fmaf(b1, fc[5], b2 * fc[8]));
            denom += w;
            r = fmaf(w, tr, r);
            g = fmaf(w, tg, g);
            b = fmaf(w, tb, b);
        }
    }

    float inv = 1.0f / denom;
    float4 o;
    o.x = (r + delta) * inv; // background = (1,1,1): + delta*1/denom
    o.y = (g + delta) * inv;
    o.z = (b + delta) * inv;
    o.w = keep;
    ((float4*)out)[p] = o;
}

extern "C" void kernel_launch(void* const* d_in, const int* in_sizes, int n_in,
                              void* d_out, int out_size, void* d_ws, size_t ws_size,
                              hipStream_t stream) {
    const int*   p2f         = (const int*)d_in[0];
    const float* bary        = (const float*)d_in[1];
    const float* zbuf        = (const float*)d_in[2];
    const float* dists       = (const float*)d_in[3];
    const float* face_colors = (const float*)d_in[4];
    float* out = (float*)d_out;

    int NP = in_sizes[0] / KFRAG; // N*H*W pixels
    int block = 256;
    int grid = (NP + block - 1) / block;
    soft_shader_kernel<<<grid, block, 0, stream>>>(
        p2f, bary, zbuf, dists, face_colors, out, NP);
}